// Round 2
// baseline (1155.484 us; speedup 1.0000x reference)
//
#include <hip/hip_runtime.h>

// ---------------------------------------------------------------------------
// GCN link predictor: 3x (GCNConv -> BN -> ReLU) -> GCNConv -> edge MLP decoder
//   - CSR build by destination (histogram -> single-block scan -> scatter)
//   - Per layer: dense GEMM (64x64 LDS tile, XOR-swizzled A-tile) ->
//     wave-per-node aggregation (no atomics) -> BN stats (f64) -> fused BN+ReLU
//   - Decoder fused: gather -> MLP1 -> MLP2 -> dot, one 64-edge tile per block
// LDS swizzle: c' = c ^ ((k&15)<<2) flips element bits 2..5 only -> float4
// reads stay contiguous/aligned; staging writes 32-way -> 8-way conflicts.
// ---------------------------------------------------------------------------

__device__ __forceinline__ float frelu(float v) { return v > 0.f ? v : 0.f; }
__device__ __forceinline__ int swz(int k, int c) { return c ^ ((k & 15) << 2); }

__global__ void init_deg_kernel(float* __restrict__ deg, int n) {
  int i = blockIdx.x * blockDim.x + threadIdx.x;
  if (i < n) deg[i] = 1.0f;  // self-loop weight
}

__global__ void deg_hist_kernel(const int* __restrict__ col, const float* __restrict__ ew,
                                float* __restrict__ deg, int* __restrict__ hist, int E) {
  int e = blockIdx.x * blockDim.x + threadIdx.x;
  if (e < E) {
    int c = col[e];
    atomicAdd(&deg[c], ew[e]);
    atomicAdd(&hist[c], 1);
  }
}

__global__ void dinv_kernel(const float* __restrict__ deg, float* __restrict__ dinv, int n) {
  int i = blockIdx.x * blockDim.x + threadIdx.x;
  if (i < n) {
    float d = deg[i];
    dinv[i] = d > 0.f ? rsqrtf(d) : 0.f;
  }
}

// Single-block exclusive scan over hist[n] -> indptr[n+1]. 1024 threads.
__global__ void scan_kernel(const int* __restrict__ hist, int* __restrict__ indptr, int n) {
  __shared__ int wsum[16];
  __shared__ int carry_s;
  int t = threadIdx.x, lane = t & 63, w = t >> 6;
  if (t == 0) carry_s = 0;
  __syncthreads();
  for (int base = 0; base < n; base += 1024) {
    int i = base + t;
    int v = (i < n) ? hist[i] : 0;
    int incl = v;
#pragma unroll
    for (int off = 1; off < 64; off <<= 1) {
      int u = __shfl_up(incl, off);
      if (lane >= off) incl += u;
    }
    if (lane == 63) wsum[w] = incl;
    __syncthreads();
    int woff = 0;
    for (int q = 0; q < w; ++q) woff += wsum[q];
    int excl = carry_s + woff + (incl - v);
    if (i < n) indptr[i] = excl;
    __syncthreads();
    if (t == 1023) carry_s += woff + incl;  // chunk total
    __syncthreads();
  }
  if (threadIdx.x == 0) indptr[n] = carry_s;
}

__global__ void scatter_kernel(const int* __restrict__ row, const int* __restrict__ col,
                               const float* __restrict__ ew, const float* __restrict__ dinv,
                               const int* __restrict__ indptr, int* __restrict__ cursor,
                               int* __restrict__ srow, float* __restrict__ snorm, int E) {
  int e = blockIdx.x * blockDim.x + threadIdx.x;
  if (e < E) {
    int c = col[e], r = row[e];
    int pos = indptr[c] + atomicAdd(&cursor[c], 1);
    srow[pos] = r;
    snorm[pos] = dinv[r] * ew[e] * dinv[c];
  }
}

// C[n,F] = A[n,K] @ W[K,F].  64x64 output tile per block, 256 threads, 4x4/thread.
template <int K>
__global__ __launch_bounds__(256) void gemm_kernel(const float* __restrict__ A,
                                                   const float* __restrict__ W,
                                                   float* __restrict__ C, int n, int F) {
  __shared__ float At[K * 64];  // At[k][swz(k,r)]
  __shared__ float Wl[K * 64];  // Wl[k][c]
  int t = threadIdx.x;
  int r0 = blockIdx.x * 64, c0 = blockIdx.y * 64;
  for (int e = t; e < 64 * K; e += 256) {
    int r = e / K, k = e % K;  // k lane-fast: coalesced global read
    At[k * 64 + swz(k, r)] = (r0 + r < n) ? A[(size_t)(r0 + r) * K + k] : 0.f;
  }
  for (int e = t; e < K * 64; e += 256) {
    int k = e >> 6, c = e & 63;
    Wl[e] = W[k * F + c0 + c];
  }
  __syncthreads();
  int tx = t & 15, ty = t >> 4;
  float acc[4][4] = {};
#pragma unroll 8
  for (int k = 0; k < K; ++k) {
    float4 a4 = *(const float4*)&At[k * 64 + swz(k, ty * 4)];
    float4 b4 = *(const float4*)&Wl[k * 64 + tx * 4];
    float a[4] = {a4.x, a4.y, a4.z, a4.w};
    float b[4] = {b4.x, b4.y, b4.z, b4.w};
#pragma unroll
    for (int i = 0; i < 4; ++i)
#pragma unroll
      for (int j = 0; j < 4; ++j) acc[i][j] = fmaf(a[i], b[j], acc[i][j]);
  }
#pragma unroll
  for (int i = 0; i < 4; ++i) {
    int r = r0 + ty * 4 + i;
    if (r < n) {
      float4 o = make_float4(acc[i][0], acc[i][1], acc[i][2], acc[i][3]);
      *(float4*)&C[(size_t)r * F + c0 + tx * 4] = o;
    }
  }
}

// One wave per node. out[i,:] = sum_e xw[srow[e],:]*snorm[e] + xw[i,:]*dinv[i]^2 + bias
template <int F>
__global__ void agg_kernel(const float* __restrict__ xw, const int* __restrict__ indptr,
                           const int* __restrict__ srow, const float* __restrict__ snorm,
                           const float* __restrict__ dinv, const float* __restrict__ bias,
                           float* __restrict__ out, int n) {
  int gid = blockIdx.x * blockDim.x + threadIdx.x;
  int i = gid >> 6, lane = gid & 63;
  if (i >= n) return;
  int beg = indptr[i], end = indptr[i + 1];
  float di = dinv[i];
  float sw = di * di;
  if (F == 128) {
    const float2* x2 = (const float2*)xw;
    float2 acc = make_float2(0.f, 0.f);
    int e = beg;
    for (; e + 1 < end; e += 2) {  // 2-deep ILP on the gather chain
      int r0 = srow[e], r1 = srow[e + 1];
      float nv0 = snorm[e], nv1 = snorm[e + 1];
      float2 v0 = x2[(size_t)r0 * 64 + lane];
      float2 v1 = x2[(size_t)r1 * 64 + lane];
      acc.x = fmaf(v0.x, nv0, acc.x);
      acc.y = fmaf(v0.y, nv0, acc.y);
      acc.x = fmaf(v1.x, nv1, acc.x);
      acc.y = fmaf(v1.y, nv1, acc.y);
    }
    if (e < end) {
      int r = srow[e];
      float nv = snorm[e];
      float2 v = x2[(size_t)r * 64 + lane];
      acc.x = fmaf(v.x, nv, acc.x);
      acc.y = fmaf(v.y, nv, acc.y);
    }
    float2 vs = x2[(size_t)i * 64 + lane];
    float2 b = ((const float2*)bias)[lane];
    acc.x = fmaf(vs.x, sw, acc.x) + b.x;
    acc.y = fmaf(vs.y, sw, acc.y) + b.y;
    ((float2*)out)[(size_t)i * 64 + lane] = acc;
  } else {
    float acc = 0.f;
    int e = beg;
    for (; e + 1 < end; e += 2) {
      int r0 = srow[e], r1 = srow[e + 1];
      float nv0 = snorm[e], nv1 = snorm[e + 1];
      float v0 = xw[(size_t)r0 * 64 + lane];
      float v1 = xw[(size_t)r1 * 64 + lane];
      acc = fmaf(v0, nv0, acc);
      acc = fmaf(v1, nv1, acc);
    }
    if (e < end) acc = fmaf(xw[(size_t)srow[e] * 64 + lane], snorm[e], acc);
    acc = fmaf(xw[(size_t)i * 64 + lane], sw, acc) + bias[lane];
    out[(size_t)i * 64 + lane] = acc;
  }
}

// 128 threads/block = one column each; 256 rows per block; f64 atomics at the end.
__global__ void bn_stats_kernel(const float* __restrict__ h, double* __restrict__ sum,
                                double* __restrict__ sumsq, int n) {
  int c = threadIdx.x;
  int r0 = blockIdx.x * 256;
  int r1 = min(r0 + 256, n);
  double s = 0.0, s2 = 0.0;
  for (int r = r0; r < r1; ++r) {
    float v = h[(size_t)r * 128 + c];
    s += v;
    s2 += (double)v * v;
  }
  atomicAdd(&sum[c], s);
  atomicAdd(&sumsq[c], s2);
}

__global__ void bn_finalize_kernel(const double* __restrict__ sum, const double* __restrict__ sumsq,
                                   const float* __restrict__ gamma, const float* __restrict__ beta,
                                   float2* __restrict__ ss, int n) {
  int c = threadIdx.x;  // 128
  double mean = sum[c] / n;
  double var = sumsq[c] / n - mean * mean;
  float inv = (float)(1.0 / sqrt(var + 1e-5));
  float scale = gamma[c] * inv;
  float shift = beta[c] - (float)mean * scale;
  ss[c] = make_float2(scale, shift);
}

__global__ void bn_apply_kernel(float* __restrict__ h, const float2* __restrict__ ss, int total4) {
  int idx = blockIdx.x * blockDim.x + threadIdx.x;
  if (idx >= total4) return;
  float4 v = ((float4*)h)[idx];
  int cb = (idx * 4) & 127;
  float2 s0 = ss[cb], s1 = ss[cb + 1], s2 = ss[cb + 2], s3 = ss[cb + 3];
  v.x = frelu(fmaf(v.x, s0.x, s0.y));
  v.y = frelu(fmaf(v.y, s1.x, s1.y));
  v.z = frelu(fmaf(v.z, s2.x, s2.y));
  v.w = frelu(fmaf(v.w, s3.x, s3.y));
  ((float4*)h)[idx] = v;
}

// Fused decoder: per block, 64 label-edges. gather z[128] -> relu(z@dw1+db1)
// -> relu(z1@dw2+db2) -> dot dw3 + db3.
__global__ __launch_bounds__(256) void decoder_kernel(
    const float* __restrict__ enc, const int* __restrict__ eli, int L,
    const float* __restrict__ dw1, const float* __restrict__ db1,
    const float* __restrict__ dw2, const float* __restrict__ db2,
    const float* __restrict__ dw3, const float* __restrict__ db3,
    float* __restrict__ out) {
  __shared__ float smem[16384];
  float* zt = smem;          // [128][64]  zt[k][swz(k,r)]
  float* w1l = smem + 8192;  // [128][64]
  int t = threadIdx.x;
  int l0 = blockIdx.x * 64;
  // stage gathered z (transposed, swizzled) — k fastest for coalescing
  for (int e = t; e < 64 * 128; e += 256) {
    int r = e >> 7, k = e & 127;
    int l = l0 + r;
    float v = 0.f;
    if (l < L) {
      int node = (k < 64) ? eli[l] : eli[L + l];
      v = enc[(size_t)node * 64 + (k & 63)];
    }
    zt[k * 64 + swz(k, r)] = v;
  }
  for (int e = t; e < 8192; e += 256) w1l[e] = dw1[e];
  __syncthreads();

  int tx = t & 15, ty = t >> 4;  // cols tx*4.., rows(edges) ty*4..
  float acc[4][4] = {};
#pragma unroll 8
  for (int k = 0; k < 128; ++k) {
    float4 a4 = *(const float4*)&zt[k * 64 + swz(k, ty * 4)];
    float4 b4 = *(const float4*)&w1l[k * 64 + tx * 4];
    float a[4] = {a4.x, a4.y, a4.z, a4.w};
    float b[4] = {b4.x, b4.y, b4.z, b4.w};
#pragma unroll
    for (int i = 0; i < 4; ++i)
#pragma unroll
      for (int j = 0; j < 4; ++j) acc[i][j] = fmaf(a[i], b[j], acc[i][j]);
  }
  __syncthreads();  // done reading zt/w1l

  float* z1t = smem;         // [64][swz]  z1t[c][swz(c,r)]
  float* w2l = smem + 4096;  // [64][64]
  float* red = smem + 8192;  // [64][17]
  float4 db1v = *(const float4*)&db1[tx * 4];
  float db1a[4] = {db1v.x, db1v.y, db1v.z, db1v.w};
#pragma unroll
  for (int j = 0; j < 4; ++j) {
    int c = tx * 4 + j;
#pragma unroll
    for (int i = 0; i < 4; ++i)
      z1t[c * 64 + swz(c, ty * 4 + i)] = frelu(acc[i][j] + db1a[j]);
  }
  for (int e = t; e < 4096; e += 256) w2l[e] = dw2[e];
  __syncthreads();

  float acc2[4][4] = {};
#pragma unroll 8
  for (int k = 0; k < 64; ++k) {
    float4 a4 = *(const float4*)&z1t[k * 64 + swz(k, ty * 4)];
    float4 b4 = *(const float4*)&w2l[k * 64 + tx * 4];
    float a[4] = {a4.x, a4.y, a4.z, a4.w};
    float b[4] = {b4.x, b4.y, b4.z, b4.w};
#pragma unroll
    for (int i = 0; i < 4; ++i)
#pragma unroll
      for (int j = 0; j < 4; ++j) acc2[i][j] = fmaf(a[i], b[j], acc2[i][j]);
  }
  float4 db2v = *(const float4*)&db2[tx * 4];
  float4 dw3v = *(const float4*)&dw3[tx * 4];
  float db2a[4] = {db2v.x, db2v.y, db2v.z, db2v.w};
  float dw3a[4] = {dw3v.x, dw3v.y, dw3v.z, dw3v.w};
#pragma unroll
  for (int i = 0; i < 4; ++i) {
    float p = 0.f;
#pragma unroll
    for (int j = 0; j < 4; ++j) p = fmaf(frelu(acc2[i][j] + db2a[j]), dw3a[j], p);
    red[(ty * 4 + i) * 17 + tx] = p;
  }
  __syncthreads();
  if (t < 64) {
    float s = 0.f;
#pragma unroll
    for (int q = 0; q < 16; ++q) s += red[t * 17 + q];
    int l = l0 + t;
    if (l < L) out[l] = s + db3[0];
  }
}

extern "C" void kernel_launch(void* const* d_in, const int* in_sizes, int n_in,
                              void* d_out, int out_size, void* d_ws, size_t ws_size,
                              hipStream_t stream) {
  const float* x = (const float*)d_in[0];
  const int* edge_index = (const int*)d_in[1];
  const float* ew = (const float*)d_in[2];
  const int* eli = (const int*)d_in[3];
  const float* w1 = (const float*)d_in[4];
  const float* b1 = (const float*)d_in[5];
  const float* w2 = (const float*)d_in[6];
  const float* b2 = (const float*)d_in[7];
  const float* w3 = (const float*)d_in[8];
  const float* b3 = (const float*)d_in[9];
  const float* w4 = (const float*)d_in[10];
  const float* b4 = (const float*)d_in[11];
  const float* bn_gamma = (const float*)d_in[12];
  const float* bn_beta = (const float*)d_in[13];
  const float* dw1 = (const float*)d_in[14];
  const float* db1 = (const float*)d_in[15];
  const float* dw2 = (const float*)d_in[16];
  const float* db2 = (const float*)d_in[17];
  const float* dw3 = (const float*)d_in[18];
  const float* db3 = (const float*)d_in[19];

  const int n = in_sizes[0] / 32;
  const int E = in_sizes[2];
  const int L = out_size;
  const int* rowv = edge_index;      // edge_index[0]
  const int* colv = edge_index + E;  // edge_index[1]

  char* ws = (char*)d_ws;
  size_t off = 0;
  float* bufA = (float*)(ws + off); off += (size_t)n * 128 * 4;
  float* bufB = (float*)(ws + off); off += (size_t)n * 128 * 4;
  float* deg = (float*)(ws + off);  off += (size_t)n * 4;
  float* dinv = (float*)(ws + off); off += (size_t)n * 4;
  int* hist = (int*)(ws + off);     off += (size_t)n * 4;
  int* cursor = (int*)(ws + off);   off += (size_t)n * 4;
  int* indptr = (int*)(ws + off);   off += (size_t)(n + 1) * 4;
  off = (off + 255) & ~(size_t)255;
  int* srow = (int*)(ws + off);     off += (size_t)E * 4;
  float* snorm = (float*)(ws + off);off += (size_t)E * 4;
  off = (off + 255) & ~(size_t)255;
  double* bnsum = (double*)(ws + off);   off += 128 * 8;
  double* bnsumsq = (double*)(ws + off); off += 128 * 8;
  float2* bnss = (float2*)(ws + off);    off += 128 * 8;

  // ---- CSR build ----
  hipMemsetAsync(hist, 0, (size_t)n * 4, stream);
  hipMemsetAsync(cursor, 0, (size_t)n * 4, stream);
  init_deg_kernel<<<(n + 255) / 256, 256, 0, stream>>>(deg, n);
  deg_hist_kernel<<<(E + 255) / 256, 256, 0, stream>>>(colv, ew, deg, hist, E);
  dinv_kernel<<<(n + 255) / 256, 256, 0, stream>>>(deg, dinv, n);
  scan_kernel<<<1, 1024, 0, stream>>>(hist, indptr, n);
  scatter_kernel<<<(E + 255) / 256, 256, 0, stream>>>(rowv, colv, ew, dinv, indptr, cursor,
                                                      srow, snorm, E);

  dim3 gemm_grid128((n + 63) / 64, 2);
  dim3 gemm_grid64((n + 63) / 64, 1);
  int agg_blocks = (n * 64 + 255) / 256;
  int bn_blocks = (n + 255) / 256;
  int apply_blocks = ((n * 128 / 4) + 255) / 256;

  // ---- layer 1: x[.,32] @ w1 -> bufA; agg -> bufB; BN+ReLU in-place ----
  gemm_kernel<32><<<gemm_grid128, 256, 0, stream>>>(x, w1, bufA, n, 128);
  agg_kernel<128><<<agg_blocks, 256, 0, stream>>>(bufA, indptr, srow, snorm, dinv, b1, bufB, n);
  hipMemsetAsync(bnsum, 0, 2 * 128 * 8, stream);
  bn_stats_kernel<<<bn_blocks, 128, 0, stream>>>(bufB, bnsum, bnsumsq, n);
  bn_finalize_kernel<<<1, 128, 0, stream>>>(bnsum, bnsumsq, bn_gamma, bn_beta, bnss, n);
  bn_apply_kernel<<<apply_blocks, 256, 0, stream>>>(bufB, bnss, n * 128 / 4);

  // ---- layer 2 ----
  gemm_kernel<128><<<gemm_grid128, 256, 0, stream>>>(bufB, w2, bufA, n, 128);
  agg_kernel<128><<<agg_blocks, 256, 0, stream>>>(bufA, indptr, srow, snorm, dinv, b2, bufB, n);
  hipMemsetAsync(bnsum, 0, 2 * 128 * 8, stream);
  bn_stats_kernel<<<bn_blocks, 128, 0, stream>>>(bufB, bnsum, bnsumsq, n);
  bn_finalize_kernel<<<1, 128, 0, stream>>>(bnsum, bnsumsq, bn_gamma + 128, bn_beta + 128, bnss, n);
  bn_apply_kernel<<<apply_blocks, 256, 0, stream>>>(bufB, bnss, n * 128 / 4);

  // ---- layer 3 ----
  gemm_kernel<128><<<gemm_grid128, 256, 0, stream>>>(bufB, w3, bufA, n, 128);
  agg_kernel<128><<<agg_blocks, 256, 0, stream>>>(bufA, indptr, srow, snorm, dinv, b3, bufB, n);
  hipMemsetAsync(bnsum, 0, 2 * 128 * 8, stream);
  bn_stats_kernel<<<bn_blocks, 128, 0, stream>>>(bufB, bnsum, bnsumsq, n);
  bn_finalize_kernel<<<1, 128, 0, stream>>>(bnsum, bnsumsq, bn_gamma + 256, bn_beta + 256, bnss, n);
  bn_apply_kernel<<<apply_blocks, 256, 0, stream>>>(bufB, bnss, n * 128 / 4);

  // ---- layer 4: enc = conv(h3, w4, b4)  [n,64] ----
  gemm_kernel<128><<<gemm_grid64, 256, 0, stream>>>(bufB, w4, bufA, n, 64);
  agg_kernel<64><<<agg_blocks, 256, 0, stream>>>(bufA, indptr, srow, snorm, dinv, b4, bufB, n);

  // ---- decoder ----
  decoder_kernel<<<(L + 63) / 64, 256, 0, stream>>>(bufB, eli, L, dw1, db1, dw2, db2, dw3, db3,
                                                    (float*)d_out);
}

// Round 8
// 863.939 us; speedup vs baseline: 1.3375x; 1.3375x over previous
//
#include <hip/hip_runtime.h>

// ---------------------------------------------------------------------------
// GCN link predictor: 3x (GCNConv -> BN -> ReLU) -> GCNConv -> edge MLP decoder
//   - CSR build by destination (histogram -> single-block scan -> scatter),
//     edge payload packed as float2 {bitcast(row), norm}
//   - Layer 1: aggregate raw x (32-dim, 128B/edge gather) FIRST, then GEMM
//     (conv commutes). Layers 2-4: GEMM (fused BN+ReLU of prev layer in
//     A-staging) -> wave-per-node aggregation (no atomics, 4-deep ILP)
//   - GEMM: 64x64 tile, K chunked in BK=64 stages -> 32KB LDS (5 blocks/CU)
//   - Decoder: first MLP layer hoisted to node level (z@dw1 = P_top[src] +
//     P_bot[dst]); per-edge kernel = gather+bias+relu -> 64x64 MLP2 -> dot
//     with shuffle reduction.
// LDS swizzle: c' = c ^ (((k>>2)&7)<<2) — XOR key uses k bits 2..4 mapped to
// element bits 2..4 (all below the 32-bank boundary, all >= float4 width):
// float4 reads stay contiguous/aligned, reads broadcast (conflict-free),
// z1t transpose-writes spread 16 lanes over 8 banks (2-way = free).
// ---------------------------------------------------------------------------

__device__ __forceinline__ float frelu(float v) { return v > 0.f ? v : 0.f; }
__device__ __forceinline__ int swz(int k, int c) { return c ^ (((k >> 2) & 7) << 2); }

__global__ void init_deg_kernel(float* __restrict__ deg, int n) {
  int i = blockIdx.x * blockDim.x + threadIdx.x;
  if (i < n) deg[i] = 1.0f;  // self-loop weight
}

__global__ void deg_hist_kernel(const int* __restrict__ col, const float* __restrict__ ew,
                                float* __restrict__ deg, int* __restrict__ hist, int E) {
  int e = blockIdx.x * blockDim.x + threadIdx.x;
  if (e < E) {
    int c = col[e];
    atomicAdd(&deg[c], ew[e]);
    atomicAdd(&hist[c], 1);
  }
}

__global__ void dinv_kernel(const float* __restrict__ deg, float* __restrict__ dinv, int n) {
  int i = blockIdx.x * blockDim.x + threadIdx.x;
  if (i < n) {
    float d = deg[i];
    dinv[i] = d > 0.f ? rsqrtf(d) : 0.f;
  }
}

// Single-block exclusive scan over hist[n] -> indptr[n+1]. 1024 threads.
__global__ void scan_kernel(const int* __restrict__ hist, int* __restrict__ indptr, int n) {
  __shared__ int wsum[16];
  __shared__ int carry_s;
  int t = threadIdx.x, lane = t & 63, w = t >> 6;
  if (t == 0) carry_s = 0;
  __syncthreads();
  for (int base = 0; base < n; base += 1024) {
    int i = base + t;
    int v = (i < n) ? hist[i] : 0;
    int incl = v;
#pragma unroll
    for (int off = 1; off < 64; off <<= 1) {
      int u = __shfl_up(incl, off);
      if (lane >= off) incl += u;
    }
    if (lane == 63) wsum[w] = incl;
    __syncthreads();
    int woff = 0;
    for (int q = 0; q < w; ++q) woff += wsum[q];
    int excl = carry_s + woff + (incl - v);
    if (i < n) indptr[i] = excl;
    __syncthreads();
    if (t == 1023) carry_s += woff + incl;  // chunk total
    __syncthreads();
  }
  if (threadIdx.x == 0) indptr[n] = carry_s;
}

// sedge[pos] = { bitcast(row), dinv[row]*ew*dinv[col] }
__global__ void scatter_kernel(const int* __restrict__ row, const int* __restrict__ col,
                               const float* __restrict__ ew, const float* __restrict__ dinv,
                               const int* __restrict__ indptr, int* __restrict__ cursor,
                               float2* __restrict__ sedge, int E) {
  int e = blockIdx.x * blockDim.x + threadIdx.x;
  if (e < E) {
    int c = col[e], r = row[e];
    int pos = indptr[c] + atomicAdd(&cursor[c], 1);
    sedge[pos] = make_float2(__int_as_float(r), dinv[r] * ew[e] * dinv[c]);
  }
}

// C[n,F] = act(A)[n,K] @ W[K,F] (+bias).  64x64 tile, 256 threads, 4x4/thread.
// K chunked in BK<=64 stages -> 32KB LDS max. If ss != nullptr, A-staging
// applies relu(a*ss[k].x + ss[k].y) (fused BN+ReLU of the previous layer).
template <int K>
__global__ __launch_bounds__(256) void gemm_kernel(const float* __restrict__ A,
                                                   const float* __restrict__ W,
                                                   float* __restrict__ C, int n, int F,
                                                   const float2* __restrict__ ss,
                                                   const float* __restrict__ bias) {
  constexpr int BK = (K > 64) ? 64 : K;
  __shared__ float At[BK * 64];  // At[kk][swz(kk,r)]
  __shared__ float Wl[BK * 64];  // Wl[kk][c]
  int t = threadIdx.x;
  int r0 = blockIdx.x * 64, c0 = blockIdx.y * 64;
  int tx = t & 15, ty = t >> 4;
  float acc[4][4] = {};
  for (int k0 = 0; k0 < K; k0 += BK) {
    if (k0) __syncthreads();  // previous chunk's compute done before overwrite
    for (int e = t; e < 64 * BK; e += 256) {
      int r = e / BK, kk = e % BK;  // kk lane-fast: coalesced global read
      int k = k0 + kk;
      float v = (r0 + r < n) ? A[(size_t)(r0 + r) * K + k] : 0.f;
      if (ss) {
        float2 s = ss[k];
        v = frelu(fmaf(v, s.x, s.y));
      }
      At[kk * 64 + swz(kk, r)] = v;
    }
    for (int e = t; e < BK * 64; e += 256) {
      int kk = e >> 6, c = e & 63;
      Wl[e] = W[(size_t)(k0 + kk) * F + c0 + c];
    }
    __syncthreads();
#pragma unroll 8
    for (int kk = 0; kk < BK; ++kk) {
      float4 a4 = *(const float4*)&At[kk * 64 + swz(kk, ty * 4)];
      float4 b4 = *(const float4*)&Wl[kk * 64 + tx * 4];
      float a[4] = {a4.x, a4.y, a4.z, a4.w};
      float b[4] = {b4.x, b4.y, b4.z, b4.w};
#pragma unroll
      for (int i = 0; i < 4; ++i)
#pragma unroll
        for (int j = 0; j < 4; ++j) acc[i][j] = fmaf(a[i], b[j], acc[i][j]);
    }
  }
  float4 bv = make_float4(0.f, 0.f, 0.f, 0.f);
  if (bias) bv = *(const float4*)&bias[c0 + tx * 4];
#pragma unroll
  for (int i = 0; i < 4; ++i) {
    int r = r0 + ty * 4 + i;
    if (r < n) {
      float4 o = make_float4(acc[i][0] + bv.x, acc[i][1] + bv.y, acc[i][2] + bv.z,
                             acc[i][3] + bv.w);
      *(float4*)&C[(size_t)r * F + c0 + tx * 4] = o;
    }
  }
}

// P[n,128]: cols 0..63 = enc @ dw1[0:64,:], cols 64..127 = enc @ dw1[64:128,:]
__global__ __launch_bounds__(256) void pre_gemm_kernel(const float* __restrict__ enc,
                                                       const float* __restrict__ dw1,
                                                       float* __restrict__ P, int n) {
  __shared__ float At[64 * 64];
  __shared__ float Wl[64 * 64];
  int t = threadIdx.x;
  int r0 = blockIdx.x * 64;
  const float* W = dw1 + blockIdx.y * 4096;  // [64,64] half of dw1
  for (int e = t; e < 64 * 64; e += 256) {
    int r = e >> 6, k = e & 63;
    At[k * 64 + swz(k, r)] = (r0 + r < n) ? enc[(size_t)(r0 + r) * 64 + k] : 0.f;
  }
  for (int e = t; e < 4096; e += 256) Wl[e] = W[e];
  __syncthreads();
  int tx = t & 15, ty = t >> 4;
  float acc[4][4] = {};
#pragma unroll 8
  for (int k = 0; k < 64; ++k) {
    float4 a4 = *(const float4*)&At[k * 64 + swz(k, ty * 4)];
    float4 b4 = *(const float4*)&Wl[k * 64 + tx * 4];
    float a[4] = {a4.x, a4.y, a4.z, a4.w};
    float b[4] = {b4.x, b4.y, b4.z, b4.w};
#pragma unroll
    for (int i = 0; i < 4; ++i)
#pragma unroll
      for (int j = 0; j < 4; ++j) acc[i][j] = fmaf(a[i], b[j], acc[i][j]);
  }
#pragma unroll
  for (int i = 0; i < 4; ++i) {
    int r = r0 + ty * 4 + i;
    if (r < n) {
      float4 o = make_float4(acc[i][0], acc[i][1], acc[i][2], acc[i][3]);
      *(float4*)&P[(size_t)r * 128 + blockIdx.y * 64 + tx * 4] = o;
    }
  }
}

// Layer-1 aggregation on raw x [n,32]: 2 nodes per wave, 32 lanes each.
// out[i,k] = sum_e x[row_e,k]*norm_e + x[i,k]*dinv[i]^2   (bias added in GEMM)
__global__ void agg32_kernel(const float* __restrict__ x, const int* __restrict__ indptr,
                             const float2* __restrict__ sedge, const float* __restrict__ dinv,
                             float* __restrict__ out, int n) {
  int gid = blockIdx.x * blockDim.x + threadIdx.x;
  int i = gid >> 5, lane = gid & 31;
  if (i >= n) return;
  int beg = indptr[i], end = indptr[i + 1];
  float di = dinv[i];
  float sw = di * di;
  float acc = 0.f;
  int e = beg;
  for (; e + 3 < end; e += 4) {
    float2 p0 = sedge[e], p1 = sedge[e + 1], p2 = sedge[e + 2], p3 = sedge[e + 3];
    float v0 = x[(size_t)__float_as_int(p0.x) * 32 + lane];
    float v1 = x[(size_t)__float_as_int(p1.x) * 32 + lane];
    float v2 = x[(size_t)__float_as_int(p2.x) * 32 + lane];
    float v3 = x[(size_t)__float_as_int(p3.x) * 32 + lane];
    acc = fmaf(v0, p0.y, acc);
    acc = fmaf(v1, p1.y, acc);
    acc = fmaf(v2, p2.y, acc);
    acc = fmaf(v3, p3.y, acc);
  }
  for (; e < end; ++e) {
    float2 p = sedge[e];
    acc = fmaf(x[(size_t)__float_as_int(p.x) * 32 + lane], p.y, acc);
  }
  acc = fmaf(x[(size_t)i * 32 + lane], sw, acc);
  out[(size_t)i * 32 + lane] = acc;
}

// One wave per node. out[i,:] = sum_e xw[row_e,:]*norm_e + xw[i,:]*dinv[i]^2 + bias
template <int F>
__global__ void agg_kernel(const float* __restrict__ xw, const int* __restrict__ indptr,
                           const float2* __restrict__ sedge, const float* __restrict__ dinv,
                           const float* __restrict__ bias, float* __restrict__ out, int n) {
  int gid = blockIdx.x * blockDim.x + threadIdx.x;
  int i = gid >> 6, lane = gid & 63;
  if (i >= n) return;
  int beg = indptr[i], end = indptr[i + 1];
  float di = dinv[i];
  float sw = di * di;
  if (F == 128) {
    const float2* x2 = (const float2*)xw;
    float2 acc = make_float2(0.f, 0.f);
    int e = beg;
    for (; e + 3 < end; e += 4) {  // 4-deep ILP on the gather chain
      float2 p0 = sedge[e], p1 = sedge[e + 1], p2 = sedge[e + 2], p3 = sedge[e + 3];
      float2 v0 = x2[(size_t)__float_as_int(p0.x) * 64 + lane];
      float2 v1 = x2[(size_t)__float_as_int(p1.x) * 64 + lane];
      float2 v2 = x2[(size_t)__float_as_int(p2.x) * 64 + lane];
      float2 v3 = x2[(size_t)__float_as_int(p3.x) * 64 + lane];
      acc.x = fmaf(v0.x, p0.y, acc.x); acc.y = fmaf(v0.y, p0.y, acc.y);
      acc.x = fmaf(v1.x, p1.y, acc.x); acc.y = fmaf(v1.y, p1.y, acc.y);
      acc.x = fmaf(v2.x, p2.y, acc.x); acc.y = fmaf(v2.y, p2.y, acc.y);
      acc.x = fmaf(v3.x, p3.y, acc.x); acc.y = fmaf(v3.y, p3.y, acc.y);
    }
    for (; e < end; ++e) {
      float2 p = sedge[e];
      float2 v = x2[(size_t)__float_as_int(p.x) * 64 + lane];
      acc.x = fmaf(v.x, p.y, acc.x);
      acc.y = fmaf(v.y, p.y, acc.y);
    }
    float2 vs = x2[(size_t)i * 64 + lane];
    float2 b = ((const float2*)bias)[lane];
    acc.x = fmaf(vs.x, sw, acc.x) + b.x;
    acc.y = fmaf(vs.y, sw, acc.y) + b.y;
    ((float2*)out)[(size_t)i * 64 + lane] = acc;
  } else {
    float acc = 0.f;
    int e = beg;
    for (; e + 3 < end; e += 4) {
      float2 p0 = sedge[e], p1 = sedge[e + 1], p2 = sedge[e + 2], p3 = sedge[e + 3];
      float v0 = xw[(size_t)__float_as_int(p0.x) * 64 + lane];
      float v1 = xw[(size_t)__float_as_int(p1.x) * 64 + lane];
      float v2 = xw[(size_t)__float_as_int(p2.x) * 64 + lane];
      float v3 = xw[(size_t)__float_as_int(p3.x) * 64 + lane];
      acc = fmaf(v0, p0.y, acc);
      acc = fmaf(v1, p1.y, acc);
      acc = fmaf(v2, p2.y, acc);
      acc = fmaf(v3, p3.y, acc);
    }
    for (; e < end; ++e) {
      float2 p = sedge[e];
      acc = fmaf(xw[(size_t)__float_as_int(p.x) * 64 + lane], p.y, acc);
    }
    acc = fmaf(xw[(size_t)i * 64 + lane], sw, acc) + bias[lane];
    out[(size_t)i * 64 + lane] = acc;
  }
}

// 128 threads/block = one column each; 256 rows per block; f64 atomics at the end.
__global__ void bn_stats_kernel(const float* __restrict__ h, double* __restrict__ sum,
                                double* __restrict__ sumsq, int n) {
  int c = threadIdx.x;
  int r0 = blockIdx.x * 256;
  int r1 = min(r0 + 256, n);
  double s = 0.0, s2 = 0.0;
  for (int r = r0; r < r1; ++r) {
    float v = h[(size_t)r * 128 + c];
    s += v;
    s2 += (double)v * v;
  }
  atomicAdd(&sum[c], s);
  atomicAdd(&sumsq[c], s2);
}

__global__ void bn_finalize_kernel(const double* __restrict__ sum, const double* __restrict__ sumsq,
                                   const float* __restrict__ gamma, const float* __restrict__ beta,
                                   float2* __restrict__ ss, int n) {
  int c = threadIdx.x;  // 128
  double mean = sum[c] / n;
  double var = sumsq[c] / n - mean * mean;
  float inv = (float)(1.0 / sqrt(var + 1e-5));
  float scale = gamma[c] * inv;
  float shift = beta[c] - (float)mean * scale;
  ss[c] = make_float2(scale, shift);
}

// Fused decoder: 64 label-edges/block. z1 = relu(P[src,0:64]+P[dst,64:128]+db1)
// -> relu(z1@dw2+db2) -> dot dw3 + db3, shuffle-reduced.
__global__ __launch_bounds__(256) void decoder_kernel(
    const float* __restrict__ P, const int* __restrict__ eli, int L,
    const float* __restrict__ db1,
    const float* __restrict__ dw2, const float* __restrict__ db2,
    const float* __restrict__ dw3, const float* __restrict__ db3,
    float* __restrict__ out) {
  __shared__ float z1t[64 * 64];  // z1t[c][swz(c,r)]
  __shared__ float w2l[64 * 64];  // w2l[k][c]
  int t = threadIdx.x;
  int l0 = blockIdx.x * 64;
  for (int e = t; e < 4096; e += 256) w2l[e] = dw2[e];
  // gather P rows (float4), add halves + bias, relu -> transposed swizzled LDS
  for (int e = t; e < 1024; e += 256) {  // 1024 float4 elements = 64 edges x 16
    int r = e >> 4, c4 = e & 15;
    int l = l0 + r;
    float4 v = make_float4(0.f, 0.f, 0.f, 0.f);
    if (l < L) {
      int src = eli[l], dst = eli[L + l];
      float4 a = *(const float4*)&P[(size_t)src * 128 + c4 * 4];
      float4 b = *(const float4*)&P[(size_t)dst * 128 + 64 + c4 * 4];
      float4 d = *(const float4*)&db1[c4 * 4];
      v.x = frelu(a.x + b.x + d.x);
      v.y = frelu(a.y + b.y + d.y);
      v.z = frelu(a.z + b.z + d.z);
      v.w = frelu(a.w + b.w + d.w);
    }
    int c = c4 * 4;
    z1t[(c + 0) * 64 + swz(c + 0, r)] = v.x;
    z1t[(c + 1) * 64 + swz(c + 1, r)] = v.y;
    z1t[(c + 2) * 64 + swz(c + 2, r)] = v.z;
    z1t[(c + 3) * 64 + swz(c + 3, r)] = v.w;
  }
  __syncthreads();

  int tx = t & 15, ty = t >> 4;  // cols tx*4.., rows(edges) ty*4..
  float acc2[4][4] = {};
#pragma unroll 8
  for (int k = 0; k < 64; ++k) {
    float4 a4 = *(const float4*)&z1t[k * 64 + swz(k, ty * 4)];
    float4 b4 = *(const float4*)&w2l[k * 64 + tx * 4];
    float a[4] = {a4.x, a4.y, a4.z, a4.w};
    float b[4] = {b4.x, b4.y, b4.z, b4.w};
#pragma unroll
    for (int i = 0; i < 4; ++i)
#pragma unroll
      for (int j = 0; j < 4; ++j) acc2[i][j] = fmaf(a[i], b[j], acc2[i][j]);
  }
  float4 db2v = *(const float4*)&db2[tx * 4];
  float4 dw3v = *(const float4*)&dw3[tx * 4];
  float db2a[4] = {db2v.x, db2v.y, db2v.z, db2v.w};
  float dw3a[4] = {dw3v.x, dw3v.y, dw3v.z, dw3v.w};
  float p[4];
#pragma unroll
  for (int i = 0; i < 4; ++i) {
    float s = 0.f;
#pragma unroll
    for (int j = 0; j < 4; ++j) s = fmaf(frelu(acc2[i][j] + db2a[j]), dw3a[j], s);
    // reduce across the 16 tx lanes of this ty group
#pragma unroll
    for (int m = 1; m < 16; m <<= 1) s += __shfl_xor(s, m);
    p[i] = s;
  }
  if (tx == 0) {
    int l = l0 + ty * 4;
    if (l + 3 < L) {
      float b3 = db3[0];
      float4 o = make_float4(p[0] + b3, p[1] + b3, p[2] + b3, p[3] + b3);
      *(float4*)&out[l] = o;
    } else {
      for (int i = 0; i < 4; ++i)
        if (l + i < L) out[l + i] = p[i] + db3[0];
    }
  }
}

extern "C" void kernel_launch(void* const* d_in, const int* in_sizes, int n_in,
                              void* d_out, int out_size, void* d_ws, size_t ws_size,
                              hipStream_t stream) {
  const float* x = (const float*)d_in[0];
  const int* edge_index = (const int*)d_in[1];
  const float* ew = (const float*)d_in[2];
  const int* eli = (const int*)d_in[3];
  const float* w1 = (const float*)d_in[4];
  const float* b1 = (const float*)d_in[5];
  const float* w2 = (const float*)d_in[6];
  const float* b2 = (const float*)d_in[7];
  const float* w3 = (const float*)d_in[8];
  const float* b3 = (const float*)d_in[9];
  const float* w4 = (const float*)d_in[10];
  const float* b4 = (const float*)d_in[11];
  const float* bn_gamma = (const float*)d_in[12];
  const float* bn_beta = (const float*)d_in[13];
  const float* dw1 = (const float*)d_in[14];
  const float* db1 = (const float*)d_in[15];
  const float* dw2 = (const float*)d_in[16];
  const float* db2 = (const float*)d_in[17];
  const float* dw3 = (const float*)d_in[18];
  const float* db3 = (const float*)d_in[19];

  const int n = in_sizes[0] / 32;
  const int E = in_sizes[2];
  const int L = out_size;
  const int* rowv = edge_index;      // edge_index[0]
  const int* colv = edge_index + E;  // edge_index[1]

  char* ws = (char*)d_ws;
  size_t off = 0;
  float* bufA = (float*)(ws + off); off += (size_t)n * 128 * 4;
  float* bufB = (float*)(ws + off); off += (size_t)n * 128 * 4;
  float* deg = (float*)(ws + off);  off += (size_t)n * 4;
  float* dinv = (float*)(ws + off); off += (size_t)n * 4;
  int* hist = (int*)(ws + off);     off += (size_t)n * 4;
  int* cursor = (int*)(ws + off);   off += (size_t)n * 4;
  int* indptr = (int*)(ws + off);   off += (size_t)(n + 1) * 4;
  off = (off + 255) & ~(size_t)255;
  float2* sedge = (float2*)(ws + off); off += (size_t)E * 8;
  off = (off + 255) & ~(size_t)255;
  double* bnsum = (double*)(ws + off);   off += 128 * 8;
  double* bnsumsq = (double*)(ws + off); off += 128 * 8;
  float2* bnss = (float2*)(ws + off);    off += 128 * 8;

  // ---- CSR build ----
  hipMemsetAsync(hist, 0, (size_t)n * 4, stream);
  hipMemsetAsync(cursor, 0, (size_t)n * 4, stream);
  init_deg_kernel<<<(n + 255) / 256, 256, 0, stream>>>(deg, n);
  deg_hist_kernel<<<(E + 255) / 256, 256, 0, stream>>>(colv, ew, deg, hist, E);
  dinv_kernel<<<(n + 255) / 256, 256, 0, stream>>>(deg, dinv, n);
  scan_kernel<<<1, 1024, 0, stream>>>(hist, indptr, n);
  scatter_kernel<<<(E + 255) / 256, 256, 0, stream>>>(rowv, colv, ew, dinv, indptr, cursor,
                                                      sedge, E);

  dim3 gemm_grid128((n + 63) / 64, 2);
  dim3 gemm_grid64((n + 63) / 64, 1);
  int agg_blocks = (n * 64 + 255) / 256;
  int agg32_blocks = (n * 32 + 255) / 256;
  int bn_blocks = (n + 255) / 256;

  // ---- layer 1: agg x (32-dim) FIRST, then GEMM 32->128 (+b1); BN stats ----
  agg32_kernel<<<agg32_blocks, 256, 0, stream>>>(x, indptr, sedge, dinv, bufA, n);
  gemm_kernel<32><<<gemm_grid128, 256, 0, stream>>>(bufA, w1, bufB, n, 128, nullptr, b1);
  hipMemsetAsync(bnsum, 0, 2 * 128 * 8, stream);
  bn_stats_kernel<<<bn_blocks, 128, 0, stream>>>(bufB, bnsum, bnsumsq, n);
  bn_finalize_kernel<<<1, 128, 0, stream>>>(bnsum, bnsumsq, bn_gamma, bn_beta, bnss, n);

  // ---- layer 2 (BN1+ReLU fused into A-staging) ----
  gemm_kernel<128><<<gemm_grid128, 256, 0, stream>>>(bufB, w2, bufA, n, 128, bnss, nullptr);
  agg_kernel<128><<<agg_blocks, 256, 0, stream>>>(bufA, indptr, sedge, dinv, b2, bufB, n);
  hipMemsetAsync(bnsum, 0, 2 * 128 * 8, stream);
  bn_stats_kernel<<<bn_blocks, 128, 0, stream>>>(bufB, bnsum, bnsumsq, n);
  bn_finalize_kernel<<<1, 128, 0, stream>>>(bnsum, bnsumsq, bn_gamma + 128, bn_beta + 128, bnss, n);

  // ---- layer 3 ----
  gemm_kernel<128><<<gemm_grid128, 256, 0, stream>>>(bufB, w3, bufA, n, 128, bnss, nullptr);
  agg_kernel<128><<<agg_blocks, 256, 0, stream>>>(bufA, indptr, sedge, dinv, b3, bufB, n);
  hipMemsetAsync(bnsum, 0, 2 * 128 * 8, stream);
  bn_stats_kernel<<<bn_blocks, 128, 0, stream>>>(bufB, bnsum, bnsumsq, n);
  bn_finalize_kernel<<<1, 128, 0, stream>>>(bnsum, bnsumsq, bn_gamma + 256, bn_beta + 256, bnss, n);

  // ---- layer 4: enc = conv(relu(bn3(h3)), w4, b4)  [n,64] ----
  gemm_kernel<128><<<gemm_grid64, 256, 0, stream>>>(bufB, w4, bufA, n, 64, bnss, nullptr);
  agg_kernel<64><<<agg_blocks, 256, 0, stream>>>(bufA, indptr, sedge, dinv, b4, bufB, n);

  // ---- decoder: P = [enc@dw1_top | enc@dw1_bot] -> fused per-edge MLP ----
  pre_gemm_kernel<<<dim3((n + 63) / 64, 2), 256, 0, stream>>>(bufB, dw1, bufA, n);
  decoder_kernel<<<(L + 63) / 64, 256, 0, stream>>>(bufA, eli, L, db1, dw2, db2, dw3, db3,
                                                    (float*)d_out);
}

// Round 9
// 808.911 us; speedup vs baseline: 1.4284x; 1.0680x over previous
//
#include <hip/hip_runtime.h>

// ---------------------------------------------------------------------------
// GCN link predictor: 3x (GCNConv -> BN -> ReLU) -> GCNConv -> edge MLP decoder
//   - CSR build, atomic-minimized (R8): hist atomic RETURNS rank -> scatter is
//     atomic-free; deg derived from CSR segments (no atomics); dinv[row]
//     folded into stored edge weight; dinv[col] hoisted to agg epilogue.
//   - Layer 1: aggregate raw x (32-dim) FIRST, then GEMM (conv commutes).
//     Layers 2-4: GEMM (fused BN+ReLU of prev layer in A-staging) ->
//     wave-per-node aggregation (no atomics, 4-deep ILP)
//   - GEMM: 64x64 tile, K chunked in BK=64 stages -> 32KB LDS
//   - Decoder: first MLP layer hoisted to node level (z@dw1 = P_top[src] +
//     P_bot[dst]); per-edge kernel = gather+bias+relu -> 64x64 MLP2 -> dot.
// LDS swizzle: c' = c ^ (((k>>2)&7)<<2) (see R4 notes).
// ---------------------------------------------------------------------------

__device__ __forceinline__ float frelu(float v) { return v > 0.f ? v : 0.f; }
__device__ __forceinline__ int swz(int k, int c) { return c ^ (((k >> 2) & 7) << 2); }

// rank[e] = arrival index of edge e within its destination bin (also builds hist)
__global__ void hist_rank_kernel(const int* __restrict__ col, int* __restrict__ hist,
                                 int* __restrict__ rank, int E) {
  int e = blockIdx.x * blockDim.x + threadIdx.x;
  if (e < E) rank[e] = atomicAdd(&hist[col[e]], 1);
}

// Single-block exclusive scan over hist[n] -> indptr[n+1]. 1024 threads.
__global__ void scan_kernel(const int* __restrict__ hist, int* __restrict__ indptr, int n) {
  __shared__ int wsum[16];
  __shared__ int carry_s;
  int t = threadIdx.x, lane = t & 63, w = t >> 6;
  if (t == 0) carry_s = 0;
  __syncthreads();
  for (int base = 0; base < n; base += 1024) {
    int i = base + t;
    int v = (i < n) ? hist[i] : 0;
    int incl = v;
#pragma unroll
    for (int off = 1; off < 64; off <<= 1) {
      int u = __shfl_up(incl, off);
      if (lane >= off) incl += u;
    }
    if (lane == 63) wsum[w] = incl;
    __syncthreads();
    int woff = 0;
    for (int q = 0; q < w; ++q) woff += wsum[q];
    int excl = carry_s + woff + (incl - v);
    if (i < n) indptr[i] = excl;
    __syncthreads();
    if (t == 1023) carry_s += woff + incl;  // chunk total
    __syncthreads();
  }
  if (threadIdx.x == 0) indptr[n] = carry_s;
}

// Atomic-free scatter: sedge[indptr[col]+rank] = { bitcast(row), ew }
__global__ void scatter_kernel(const int* __restrict__ row, const int* __restrict__ col,
                               const float* __restrict__ ew, const int* __restrict__ indptr,
                               const int* __restrict__ rank, float2* __restrict__ sedge, int E) {
  int e = blockIdx.x * blockDim.x + threadIdx.x;
  if (e < E) {
    int pos = indptr[col[e]] + rank[e];
    sedge[pos] = make_float2(__int_as_float(row[e]), ew[e]);
  }
}

// deg from CSR segments (no atomics): deg[i] = 1 (self) + sum ew; dinv = rsqrt
__global__ void deg_dinv_kernel(const float2* __restrict__ sedge, const int* __restrict__ indptr,
                                float* __restrict__ dinv, int n) {
  int i = blockIdx.x * blockDim.x + threadIdx.x;
  if (i >= n) return;
  int beg = indptr[i], end = indptr[i + 1];
  float s = 1.0f;  // self-loop weight
  for (int e = beg; e < end; ++e) s += sedge[e].y;
  dinv[i] = rsqrtf(s);
}

// Fold dinv[row] into the stored weight: sedge[p].y *= dinv[row_p]
__global__ void edgew_kernel(float2* __restrict__ sedge, const float* __restrict__ dinv, int E) {
  int p = blockIdx.x * blockDim.x + threadIdx.x;
  if (p < E) {
    float2 v = sedge[p];
    v.y *= dinv[__float_as_int(v.x)];
    sedge[p] = v;
  }
}

// C[n,F] = act(A)[n,K] @ W[K,F] (+bias).  64x64 tile, 256 threads, 4x4/thread.
// K chunked in BK<=64 stages -> 32KB LDS max. If ss != nullptr, A-staging
// applies relu(a*ss[k].x + ss[k].y) (fused BN+ReLU of the previous layer).
template <int K>
__global__ __launch_bounds__(256) void gemm_kernel(const float* __restrict__ A,
                                                   const float* __restrict__ W,
                                                   float* __restrict__ C, int n, int F,
                                                   const float2* __restrict__ ss,
                                                   const float* __restrict__ bias) {
  constexpr int BK = (K > 64) ? 64 : K;
  __shared__ float At[BK * 64];  // At[kk][swz(kk,r)]
  __shared__ float Wl[BK * 64];  // Wl[kk][c]
  int t = threadIdx.x;
  int r0 = blockIdx.x * 64, c0 = blockIdx.y * 64;
  int tx = t & 15, ty = t >> 4;
  float acc[4][4] = {};
  for (int k0 = 0; k0 < K; k0 += BK) {
    if (k0) __syncthreads();  // previous chunk's compute done before overwrite
    for (int e = t; e < 64 * BK; e += 256) {
      int r = e / BK, kk = e % BK;  // kk lane-fast: coalesced global read
      int k = k0 + kk;
      float v = (r0 + r < n) ? A[(size_t)(r0 + r) * K + k] : 0.f;
      if (ss) {
        float2 s = ss[k];
        v = frelu(fmaf(v, s.x, s.y));
      }
      At[kk * 64 + swz(kk, r)] = v;
    }
    for (int e = t; e < BK * 64; e += 256) {
      int kk = e >> 6, c = e & 63;
      Wl[e] = W[(size_t)(k0 + kk) * F + c0 + c];
    }
    __syncthreads();
#pragma unroll 8
    for (int kk = 0; kk < BK; ++kk) {
      float4 a4 = *(const float4*)&At[kk * 64 + swz(kk, ty * 4)];
      float4 b4 = *(const float4*)&Wl[kk * 64 + tx * 4];
      float a[4] = {a4.x, a4.y, a4.z, a4.w};
      float b[4] = {b4.x, b4.y, b4.z, b4.w};
#pragma unroll
      for (int i = 0; i < 4; ++i)
#pragma unroll
        for (int j = 0; j < 4; ++j) acc[i][j] = fmaf(a[i], b[j], acc[i][j]);
    }
  }
  float4 bv = make_float4(0.f, 0.f, 0.f, 0.f);
  if (bias) bv = *(const float4*)&bias[c0 + tx * 4];
#pragma unroll
  for (int i = 0; i < 4; ++i) {
    int r = r0 + ty * 4 + i;
    if (r < n) {
      float4 o = make_float4(acc[i][0] + bv.x, acc[i][1] + bv.y, acc[i][2] + bv.z,
                             acc[i][3] + bv.w);
      *(float4*)&C[(size_t)r * F + c0 + tx * 4] = o;
    }
  }
}

// P[n,128]: cols 0..63 = enc @ dw1[0:64,:], cols 64..127 = enc @ dw1[64:128,:]
__global__ __launch_bounds__(256) void pre_gemm_kernel(const float* __restrict__ enc,
                                                       const float* __restrict__ dw1,
                                                       float* __restrict__ P, int n) {
  __shared__ float At[64 * 64];
  __shared__ float Wl[64 * 64];
  int t = threadIdx.x;
  int r0 = blockIdx.x * 64;
  const float* W = dw1 + blockIdx.y * 4096;  // [64,64] half of dw1
  for (int e = t; e < 64 * 64; e += 256) {
    int r = e >> 6, k = e & 63;
    At[k * 64 + swz(k, r)] = (r0 + r < n) ? enc[(size_t)(r0 + r) * 64 + k] : 0.f;
  }
  for (int e = t; e < 4096; e += 256) Wl[e] = W[e];
  __syncthreads();
  int tx = t & 15, ty = t >> 4;
  float acc[4][4] = {};
#pragma unroll 8
  for (int k = 0; k < 64; ++k) {
    float4 a4 = *(const float4*)&At[k * 64 + swz(k, ty * 4)];
    float4 b4 = *(const float4*)&Wl[k * 64 + tx * 4];
    float a[4] = {a4.x, a4.y, a4.z, a4.w};
    float b[4] = {b4.x, b4.y, b4.z, b4.w};
#pragma unroll
    for (int i = 0; i < 4; ++i)
#pragma unroll
      for (int j = 0; j < 4; ++j) acc[i][j] = fmaf(a[i], b[j], acc[i][j]);
  }
#pragma unroll
  for (int i = 0; i < 4; ++i) {
    int r = r0 + ty * 4 + i;
    if (r < n) {
      float4 o = make_float4(acc[i][0], acc[i][1], acc[i][2], acc[i][3]);
      *(float4*)&P[(size_t)r * 128 + blockIdx.y * 64 + tx * 4] = o;
    }
  }
}

// Layer-1 aggregation on raw x [n,32]: 2 nodes per wave, 32 lanes each.
// sedge.y = dinv[row]*ew.  out[i,k] = dinv[i]*( sum_e w_e*x[row_e,k] + dinv[i]*x[i,k] )
__global__ void agg32_kernel(const float* __restrict__ x, const int* __restrict__ indptr,
                             const float2* __restrict__ sedge, const float* __restrict__ dinv,
                             float* __restrict__ out, int n) {
  int gid = blockIdx.x * blockDim.x + threadIdx.x;
  int i = gid >> 5, lane = gid & 31;
  if (i >= n) return;
  int beg = indptr[i], end = indptr[i + 1];
  float di = dinv[i];
  float acc = 0.f;
  int e = beg;
  for (; e + 3 < end; e += 4) {
    float2 p0 = sedge[e], p1 = sedge[e + 1], p2 = sedge[e + 2], p3 = sedge[e + 3];
    float v0 = x[(size_t)__float_as_int(p0.x) * 32 + lane];
    float v1 = x[(size_t)__float_as_int(p1.x) * 32 + lane];
    float v2 = x[(size_t)__float_as_int(p2.x) * 32 + lane];
    float v3 = x[(size_t)__float_as_int(p3.x) * 32 + lane];
    acc = fmaf(v0, p0.y, acc);
    acc = fmaf(v1, p1.y, acc);
    acc = fmaf(v2, p2.y, acc);
    acc = fmaf(v3, p3.y, acc);
  }
  for (; e < end; ++e) {
    float2 p = sedge[e];
    acc = fmaf(x[(size_t)__float_as_int(p.x) * 32 + lane], p.y, acc);
  }
  acc = fmaf(x[(size_t)i * 32 + lane], di, acc);  // self-loop: weight dinv[i]
  out[(size_t)i * 32 + lane] = acc * di;          // hoisted dinv[col]
}

// One wave per node. sedge.y = dinv[row]*ew.
// out[i,:] = dinv[i]*( sum_e w_e*xw[row_e,:] + dinv[i]*xw[i,:] ) + bias
template <int F>
__global__ void agg_kernel(const float* __restrict__ xw, const int* __restrict__ indptr,
                           const float2* __restrict__ sedge, const float* __restrict__ dinv,
                           const float* __restrict__ bias, float* __restrict__ out, int n) {
  int gid = blockIdx.x * blockDim.x + threadIdx.x;
  int i = gid >> 6, lane = gid & 63;
  if (i >= n) return;
  int beg = indptr[i], end = indptr[i + 1];
  float di = dinv[i];
  if (F == 128) {
    const float2* x2 = (const float2*)xw;
    float2 acc = make_float2(0.f, 0.f);
    int e = beg;
    for (; e + 3 < end; e += 4) {  // 4-deep ILP on the gather chain
      float2 p0 = sedge[e], p1 = sedge[e + 1], p2 = sedge[e + 2], p3 = sedge[e + 3];
      float2 v0 = x2[(size_t)__float_as_int(p0.x) * 64 + lane];
      float2 v1 = x2[(size_t)__float_as_int(p1.x) * 64 + lane];
      float2 v2 = x2[(size_t)__float_as_int(p2.x) * 64 + lane];
      float2 v3 = x2[(size_t)__float_as_int(p3.x) * 64 + lane];
      acc.x = fmaf(v0.x, p0.y, acc.x); acc.y = fmaf(v0.y, p0.y, acc.y);
      acc.x = fmaf(v1.x, p1.y, acc.x); acc.y = fmaf(v1.y, p1.y, acc.y);
      acc.x = fmaf(v2.x, p2.y, acc.x); acc.y = fmaf(v2.y, p2.y, acc.y);
      acc.x = fmaf(v3.x, p3.y, acc.x); acc.y = fmaf(v3.y, p3.y, acc.y);
    }
    for (; e < end; ++e) {
      float2 p = sedge[e];
      float2 v = x2[(size_t)__float_as_int(p.x) * 64 + lane];
      acc.x = fmaf(v.x, p.y, acc.x);
      acc.y = fmaf(v.y, p.y, acc.y);
    }
    float2 vs = x2[(size_t)i * 64 + lane];
    float2 b = ((const float2*)bias)[lane];
    acc.x = fmaf(vs.x, di, acc.x);
    acc.y = fmaf(vs.y, di, acc.y);
    acc.x = fmaf(acc.x, di, b.x);
    acc.y = fmaf(acc.y, di, b.y);
    ((float2*)out)[(size_t)i * 64 + lane] = acc;
  } else {
    float acc = 0.f;
    int e = beg;
    for (; e + 3 < end; e += 4) {
      float2 p0 = sedge[e], p1 = sedge[e + 1], p2 = sedge[e + 2], p3 = sedge[e + 3];
      float v0 = xw[(size_t)__float_as_int(p0.x) * 64 + lane];
      float v1 = xw[(size_t)__float_as_int(p1.x) * 64 + lane];
      float v2 = xw[(size_t)__float_as_int(p2.x) * 64 + lane];
      float v3 = xw[(size_t)__float_as_int(p3.x) * 64 + lane];
      acc = fmaf(v0, p0.y, acc);
      acc = fmaf(v1, p1.y, acc);
      acc = fmaf(v2, p2.y, acc);
      acc = fmaf(v3, p3.y, acc);
    }
    for (; e < end; ++e) {
      float2 p = sedge[e];
      acc = fmaf(xw[(size_t)__float_as_int(p.x) * 64 + lane], p.y, acc);
    }
    acc = fmaf(xw[(size_t)i * 64 + lane], di, acc);
    out[(size_t)i * 64 + lane] = fmaf(acc, di, bias[lane]);
  }
}

// 128 threads/block = one column each; 256 rows per block; f64 atomics at the end.
__global__ void bn_stats_kernel(const float* __restrict__ h, double* __restrict__ sum,
                                double* __restrict__ sumsq, int n) {
  int c = threadIdx.x;
  int r0 = blockIdx.x * 256;
  int r1 = min(r0 + 256, n);
  double s = 0.0, s2 = 0.0;
  for (int r = r0; r < r1; ++r) {
    float v = h[(size_t)r * 128 + c];
    s += v;
    s2 += (double)v * v;
  }
  atomicAdd(&sum[c], s);
  atomicAdd(&sumsq[c], s2);
}

__global__ void bn_finalize_kernel(const double* __restrict__ sum, const double* __restrict__ sumsq,
                                   const float* __restrict__ gamma, const float* __restrict__ beta,
                                   float2* __restrict__ ss, int n) {
  int c = threadIdx.x;  // 128
  double mean = sum[c] / n;
  double var = sumsq[c] / n - mean * mean;
  float inv = (float)(1.0 / sqrt(var + 1e-5));
  float scale = gamma[c] * inv;
  float shift = beta[c] - (float)mean * scale;
  ss[c] = make_float2(scale, shift);
}

// Fused decoder: 64 label-edges/block. z1 = relu(P[src,0:64]+P[dst,64:128]+db1)
// -> relu(z1@dw2+db2) -> dot dw3 + db3, shuffle-reduced.
__global__ __launch_bounds__(256) void decoder_kernel(
    const float* __restrict__ P, const int* __restrict__ eli, int L,
    const float* __restrict__ db1,
    const float* __restrict__ dw2, const float* __restrict__ db2,
    const float* __restrict__ dw3, const float* __restrict__ db3,
    float* __restrict__ out) {
  __shared__ float z1t[64 * 64];  // z1t[c][swz(c,r)]
  __shared__ float w2l[64 * 64];  // w2l[k][c]
  int t = threadIdx.x;
  int l0 = blockIdx.x * 64;
  for (int e = t; e < 4096; e += 256) w2l[e] = dw2[e];
  // gather P rows (float4), add halves + bias, relu -> transposed swizzled LDS
  for (int e = t; e < 1024; e += 256) {  // 1024 float4 elements = 64 edges x 16
    int r = e >> 4, c4 = e & 15;
    int l = l0 + r;
    float4 v = make_float4(0.f, 0.f, 0.f, 0.f);
    if (l < L) {
      int src = eli[l], dst = eli[L + l];
      float4 a = *(const float4*)&P[(size_t)src * 128 + c4 * 4];
      float4 b = *(const float4*)&P[(size_t)dst * 128 + 64 + c4 * 4];
      float4 d = *(const float4*)&db1[c4 * 4];
      v.x = frelu(a.x + b.x + d.x);
      v.y = frelu(a.y + b.y + d.y);
      v.z = frelu(a.z + b.z + d.z);
      v.w = frelu(a.w + b.w + d.w);
    }
    int c = c4 * 4;
    z1t[(c + 0) * 64 + swz(c + 0, r)] = v.x;
    z1t[(c + 1) * 64 + swz(c + 1, r)] = v.y;
    z1t[(c + 2) * 64 + swz(c + 2, r)] = v.z;
    z1t[(c + 3) * 64 + swz(c + 3, r)] = v.w;
  }
  __syncthreads();

  int tx = t & 15, ty = t >> 4;  // cols tx*4.., rows(edges) ty*4..
  float acc2[4][4] = {};
#pragma unroll 8
  for (int k = 0; k < 64; ++k) {
    float4 a4 = *(const float4*)&z1t[k * 64 + swz(k, ty * 4)];
    float4 b4 = *(const float4*)&w2l[k * 64 + tx * 4];
    float a[4] = {a4.x, a4.y, a4.z, a4.w};
    float b[4] = {b4.x, b4.y, b4.z, b4.w};
#pragma unroll
    for (int i = 0; i < 4; ++i)
#pragma unroll
      for (int j = 0; j < 4; ++j) acc2[i][j] = fmaf(a[i], b[j], acc2[i][j]);
  }
  float4 db2v = *(const float4*)&db2[tx * 4];
  float4 dw3v = *(const float4*)&dw3[tx * 4];
  float db2a[4] = {db2v.x, db2v.y, db2v.z, db2v.w};
  float dw3a[4] = {dw3v.x, dw3v.y, dw3v.z, dw3v.w};
  float p[4];
#pragma unroll
  for (int i = 0; i < 4; ++i) {
    float s = 0.f;
#pragma unroll
    for (int j = 0; j < 4; ++j) s = fmaf(frelu(acc2[i][j] + db2a[j]), dw3a[j], s);
    // reduce across the 16 tx lanes of this ty group
#pragma unroll
    for (int m = 1; m < 16; m <<= 1) s += __shfl_xor(s, m);
    p[i] = s;
  }
  if (tx == 0) {
    int l = l0 + ty * 4;
    if (l + 3 < L) {
      float b3 = db3[0];
      float4 o = make_float4(p[0] + b3, p[1] + b3, p[2] + b3, p[3] + b3);
      *(float4*)&out[l] = o;
    } else {
      for (int i = 0; i < 4; ++i)
        if (l + i < L) out[l + i] = p[i] + db3[0];
    }
  }
}

extern "C" void kernel_launch(void* const* d_in, const int* in_sizes, int n_in,
                              void* d_out, int out_size, void* d_ws, size_t ws_size,
                              hipStream_t stream) {
  const float* x = (const float*)d_in[0];
  const int* edge_index = (const int*)d_in[1];
  const float* ew = (const float*)d_in[2];
  const int* eli = (const int*)d_in[3];
  const float* w1 = (const float*)d_in[4];
  const float* b1 = (const float*)d_in[5];
  const float* w2 = (const float*)d_in[6];
  const float* b2 = (const float*)d_in[7];
  const float* w3 = (const float*)d_in[8];
  const float* b3 = (const float*)d_in[9];
  const float* w4 = (const float*)d_in[10];
  const float* b4 = (const float*)d_in[11];
  const float* bn_gamma = (const float*)d_in[12];
  const float* bn_beta = (const float*)d_in[13];
  const float* dw1 = (const float*)d_in[14];
  const float* db1 = (const float*)d_in[15];
  const float* dw2 = (const float*)d_in[16];
  const float* db2 = (const float*)d_in[17];
  const float* dw3 = (const float*)d_in[18];
  const float* db3 = (const float*)d_in[19];

  const int n = in_sizes[0] / 32;
  const int E = in_sizes[2];
  const int L = out_size;
  const int* rowv = edge_index;      // edge_index[0]
  const int* colv = edge_index + E;  // edge_index[1]

  char* ws = (char*)d_ws;
  size_t off = 0;
  float* bufA = (float*)(ws + off); off += (size_t)n * 128 * 4;
  float* bufB = (float*)(ws + off); off += (size_t)n * 128 * 4;
  float* dinv = (float*)(ws + off); off += (size_t)n * 4;
  int* hist = (int*)(ws + off);     off += (size_t)n * 4;
  int* indptr = (int*)(ws + off);   off += (size_t)(n + 1) * 4;
  off = (off + 255) & ~(size_t)255;
  int* rank = (int*)(ws + off);     off += (size_t)E * 4;
  off = (off + 255) & ~(size_t)255;
  float2* sedge = (float2*)(ws + off); off += (size_t)E * 8;
  off = (off + 255) & ~(size_t)255;
  double* bnsum = (double*)(ws + off);   off += 128 * 8;
  double* bnsumsq = (double*)(ws + off); off += 128 * 8;
  float2* bnss = (float2*)(ws + off);    off += 128 * 8;

  int eblocks = (E + 255) / 256;
  int nblocks = (n + 255) / 256;

  // ---- CSR build (single atomic pass) ----
  hipMemsetAsync(hist, 0, (size_t)n * 4, stream);
  hist_rank_kernel<<<eblocks, 256, 0, stream>>>(colv, hist, rank, E);
  scan_kernel<<<1, 1024, 0, stream>>>(hist, indptr, n);
  scatter_kernel<<<eblocks, 256, 0, stream>>>(rowv, colv, ew, indptr, rank, sedge, E);
  deg_dinv_kernel<<<nblocks, 256, 0, stream>>>(sedge, indptr, dinv, n);
  edgew_kernel<<<eblocks, 256, 0, stream>>>(sedge, dinv, E);

  dim3 gemm_grid128((n + 63) / 64, 2);
  dim3 gemm_grid64((n + 63) / 64, 1);
  int agg_blocks = (n * 64 + 255) / 256;
  int agg32_blocks = (n * 32 + 255) / 256;
  int bn_blocks = (n + 255) / 256;

  // ---- layer 1: agg x (32-dim) FIRST, then GEMM 32->128 (+b1); BN stats ----
  agg32_kernel<<<agg32_blocks, 256, 0, stream>>>(x, indptr, sedge, dinv, bufA, n);
  gemm_kernel<32><<<gemm_grid128, 256, 0, stream>>>(bufA, w1, bufB, n, 128, nullptr, b1);
  hipMemsetAsync(bnsum, 0, 2 * 128 * 8, stream);
  bn_stats_kernel<<<bn_blocks, 128, 0, stream>>>(bufB, bnsum, bnsumsq, n);
  bn_finalize_kernel<<<1, 128, 0, stream>>>(bnsum, bnsumsq, bn_gamma, bn_beta, bnss, n);

  // ---- layer 2 (BN1+ReLU fused into A-staging) ----
  gemm_kernel<128><<<gemm_grid128, 256, 0, stream>>>(bufB, w2, bufA, n, 128, bnss, nullptr);
  agg_kernel<128><<<agg_blocks, 256, 0, stream>>>(bufA, indptr, sedge, dinv, b2, bufB, n);
  hipMemsetAsync(bnsum, 0, 2 * 128 * 8, stream);
  bn_stats_kernel<<<bn_blocks, 128, 0, stream>>>(bufB, bnsum, bnsumsq, n);
  bn_finalize_kernel<<<1, 128, 0, stream>>>(bnsum, bnsumsq, bn_gamma + 128, bn_beta + 128, bnss, n);

  // ---- layer 3 ----
  gemm_kernel<128><<<gemm_grid128, 256, 0, stream>>>(bufB, w3, bufA, n, 128, bnss, nullptr);
  agg_kernel<128><<<agg_blocks, 256, 0, stream>>>(bufA, indptr, sedge, dinv, b3, bufB, n);
  hipMemsetAsync(bnsum, 0, 2 * 128 * 8, stream);
  bn_stats_kernel<<<bn_blocks, 128, 0, stream>>>(bufB, bnsum, bnsumsq, n);
  bn_finalize_kernel<<<1, 128, 0, stream>>>(bnsum, bnsumsq, bn_gamma + 256, bn_beta + 256, bnss, n);

  // ---- layer 4: enc = conv(relu(bn3(h3)), w4, b4)  [n,64] ----
  gemm_kernel<128><<<gemm_grid64, 256, 0, stream>>>(bufB, w4, bufA, n, 64, bnss, nullptr);
  agg_kernel<64><<<agg_blocks, 256, 0, stream>>>(bufA, indptr, sedge, dinv, b4, bufB, n);

  // ---- decoder: P = [enc@dw1_top | enc@dw1_bot] -> fused per-edge MLP ----
  pre_gemm_kernel<<<dim3((n + 63) / 64, 2), 256, 0, stream>>>(bufB, dw1, bufA, n);
  decoder_kernel<<<(L + 63) / 64, 256, 0, stream>>>(bufA, eli, L, db1, dw2, db2, dw3, db3,
                                                    (float*)d_out);
}